// Round 5
// baseline (162.933 us; speedup 1.0000x reference)
//
#include <hip/hip_runtime.h>
#include <math.h>

#define NB 2048
#define ND 784
#define NK 128
#define BM 64               // rows per k_main block (8 ty x 8 rows each)
#define DSPLIT 28           // D chunks -> partials
#define DPB 28              // dims per block = one LDS stage
#define KD (ND * NK)        // 100352
#define TBL (ND * 3 * NK)   // interleaved table floats = 301056

// ws layout (floats): T[TBL] | lw[NK] | part[DSPLIT*NB*NK]

__global__ __launch_bounds__(256) void k_tables(
    const float* __restrict__ w, const float* __restrict__ mu,
    const float* __restrict__ cov, float* __restrict__ ws) {
  int idx = blockIdx.x * 256 + threadIdx.x;   // grid covers KD exactly
  float* T  = ws;
  float* lw = ws + TBL;
  int d = idx >> 7;
  int k = idx & (NK - 1);
  float c = cov[k * ND + d];
  float m = mu[k * ND + d];
  float inv2 = 0.5f / c;
  T[d * 384 + k]       = -inv2;                           // ta
  T[d * 384 + 128 + k] = m / c;                           // tb
  T[d * 384 + 256 + k] = -m * m * inv2 - 0.5f * logf(c);  // tc
  if (idx < NK) lw[idx] = logf(w[idx]);
}

// Grid: (NB/BM)*DSPLIT = 32*28 = 896 blocks, 256 threads.
// tx=tid&31 -> k-quad, ty=tid>>5 -> 8-row group. One 43 KB LDS table stage.
// Software pipeline: row rr's x/m for group g+1 issued right after rr's FMAs
// for group g (rotate-in-place single buffer, ~1 group of latency cover).
__global__ __launch_bounds__(256, 3) void k_main(
    const float* __restrict__ data, const float* __restrict__ mask,
    const float* __restrict__ ws, float* __restrict__ part) {
  __shared__ float lds[DPB * 384];   // 43008 B

  const float* T = ws;
  int mt  = blockIdx.x / DSPLIT;
  int dsp = blockIdx.x % DSPLIT;
  int r0  = mt * BM + (threadIdx.x >> 5) * 8;
  int d0  = dsp * DPB;
  int kb  = (threadIdx.x & 31) << 2;

  const float* dbase = data + (size_t)r0 * ND + d0;
  const float* mbase = mask + (size_t)r0 * ND + d0;

  // issue group-0 x/m loads first: their latency hides under staging+barrier
  float4 xv[8], mv[8];
#pragma unroll
  for (int rr = 0; rr < 8; rr++) {
    xv[rr] = *(const float4*)(dbase + rr * ND);
    mv[rr] = *(const float4*)(mbase + rr * ND);
  }

  // stage the table slice: 28 dims * 384 floats = 2688 float4
  {
    const float4* src = (const float4*)(T + (size_t)d0 * 384);
    float4* dst = (float4*)lds;
    for (int i = threadIdx.x; i < DPB * 96; i += 256) dst[i] = src[i];
  }
  __syncthreads();

  float acc[8][4];
#pragma unroll
  for (int i = 0; i < 8; i++)
#pragma unroll
    for (int j = 0; j < 4; j++) acc[i][j] = 0.f;

#pragma unroll 1
  for (int dg = 0; dg < DPB; dg += 4) {
    float4 a[4], b[4], c[4];
#pragma unroll
    for (int dd = 0; dd < 4; dd++) {
      const float* base = lds + (dg + dd) * 384 + kb;
      a[dd] = *(const float4*)(base);
      b[dd] = *(const float4*)(base + 128);
      c[dd] = *(const float4*)(base + 256);
    }
    bool more = (dg + 4) < DPB;
#pragma unroll
    for (int rr = 0; rr < 8; rr++) {
      float xs[4] = {xv[rr].x, xv[rr].y, xv[rr].z, xv[rr].w};
      float ms[4] = {mv[rr].x, mv[rr].y, mv[rr].z, mv[rr].w};
#pragma unroll
      for (int dd = 0; dd < 4; dd++) {
        float m0 = ms[dd];
        float m1 = m0 * xs[dd];
        float m2 = m1 * xs[dd];
        acc[rr][0] = fmaf(m2, a[dd].x, fmaf(m1, b[dd].x, fmaf(m0, c[dd].x, acc[rr][0])));
        acc[rr][1] = fmaf(m2, a[dd].y, fmaf(m1, b[dd].y, fmaf(m0, c[dd].y, acc[rr][1])));
        acc[rr][2] = fmaf(m2, a[dd].z, fmaf(m1, b[dd].z, fmaf(m0, c[dd].z, acc[rr][2])));
        acc[rr][3] = fmaf(m2, a[dd].w, fmaf(m1, b[dd].w, fmaf(m0, c[dd].w, acc[rr][3])));
      }
      if (more) {   // prefetch this row's next group: registers just went dead
        xv[rr] = *(const float4*)(dbase + rr * ND + dg + 4);
        mv[rr] = *(const float4*)(mbase + rr * ND + dg + 4);
      }
    }
  }

#pragma unroll
  for (int rr = 0; rr < 8; rr++) {
    float4 v = make_float4(acc[rr][0], acc[rr][1], acc[rr][2], acc[rr][3]);
    *(float4*)(part + ((size_t)dsp * NB + r0 + rr) * NK + kb) = v;
  }
}

// 2 rows per wave, float4 per lane (k-quad). Reduce DSPLIT partials, +log w,
// NaN fix, LSE with the reference's per-term +1e-8 (4e-8 per lane), exp.
__global__ __launch_bounds__(256) void k_final(
    const float* __restrict__ ws, float* __restrict__ out) {
  const float4* lw4   = (const float4*)(ws + TBL);
  const float4* part4 = (const float4*)(ws + TBL + NK);
  int lane = threadIdx.x & 63;
  int wv   = threadIdx.x >> 6;
  int half = lane >> 5;          // row within wave
  int lk   = lane & 31;          // k-quad index
  int b = blockIdx.x * 8 + wv * 2 + half;

  float4 s = make_float4(0.f, 0.f, 0.f, 0.f);
#pragma unroll
  for (int sp = 0; sp < DSPLIT; sp++) {
    float4 v = part4[((size_t)sp * NB + b) * 32 + lk];
    s.x += v.x; s.y += v.y; s.z += v.z; s.w += v.w;
  }
  float4 l = lw4[lk];
  s.x += l.x; s.y += l.y; s.z += l.z; s.w += l.w;
  if (isnan(s.x)) s.x = 0.f;
  if (isnan(s.y)) s.y = 0.f;
  if (isnan(s.z)) s.z = 0.f;
  if (isnan(s.w)) s.w = 0.f;

  float mx = fmaxf(fmaxf(s.x, s.y), fmaxf(s.z, s.w));
#pragma unroll
  for (int off = 16; off; off >>= 1) mx = fmaxf(mx, __shfl_xor(mx, off));
  float sum = expf(s.x - mx) + expf(s.y - mx) + expf(s.z - mx) + expf(s.w - mx) + 4e-8f;
#pragma unroll
  for (int off = 16; off; off >>= 1) sum += __shfl_xor(sum, off);
  float lse = logf(sum) + mx;
  float4 o = make_float4(expf(s.x - lse), expf(s.y - lse),
                         expf(s.z - lse), expf(s.w - lse));
  ((float4*)out)[(size_t)b * 32 + lk] = o;
}

extern "C" void kernel_launch(void* const* d_in, const int* in_sizes, int n_in,
                              void* d_out, int out_size, void* d_ws, size_t ws_size,
                              hipStream_t stream) {
  const float* data = (const float*)d_in[0];
  const float* mask = (const float*)d_in[1];
  const float* wts  = (const float*)d_in[2];
  const float* mu   = (const float*)d_in[3];
  const float* cov  = (const float*)d_in[4];
  float* ws   = (float*)d_ws;
  float* part = ws + TBL + NK;
  float* out  = (float*)d_out;

  k_tables<<<KD / 256, 256, 0, stream>>>(wts, mu, cov, ws);
  k_main<<<(NB / BM) * DSPLIT, 256, 0, stream>>>(data, mask, ws, part);
  k_final<<<NB / 8, 256, 0, stream>>>(ws, out);
}

// Round 6
// 50.340 us; speedup vs baseline: 3.2367x; 3.2367x over previous
//
#include <hip/hip_runtime.h>
#include <math.h>

#define NB 2048
#define ND 784
#define NK 128
#define BM 64               // rows per k_main block (8 ty x 8 rows each)
#define DSPLIT 49           // D chunks -> partials
#define DPB 16              // dims per block = one LDS stage (24.6 KB)
#define KD (ND * NK)        // 100352
#define TBL (ND * 3 * NK)   // interleaved table floats = 301056

// ws layout (floats): T[TBL] | lw[NK] | part[DSPLIT*NB*NK]  (~52.6 MB)

__global__ __launch_bounds__(256) void k_tables(
    const float* __restrict__ w, const float* __restrict__ mu,
    const float* __restrict__ cov, float* __restrict__ ws) {
  int idx = blockIdx.x * 256 + threadIdx.x;   // grid covers KD exactly
  float* T  = ws;
  float* lw = ws + TBL;
  int d = idx >> 7;
  int k = idx & (NK - 1);
  float c = cov[k * ND + d];
  float m = mu[k * ND + d];
  float inv2 = 0.5f / c;
  T[d * 384 + k]       = -inv2;                           // ta
  T[d * 384 + 128 + k] = m / c;                           // tb
  T[d * 384 + 256 + k] = -m * m * inv2 - 0.5f * logf(c);  // tc
  if (idx < NK) lw[idx] = logf(w[idx]);
}

// Grid: (NB/BM)*DSPLIT = 32*49 = 1568 blocks, 256 threads.
// tx=tid&31 -> k-quad, ty=tid>>5 -> 8-row group.
// LDS stage = 16 dims * 384 floats = 24576 B -> 4 blocks/CU = 16 waves/CU.
// Per dg-group: issue all 16 x/m broadcast loads up front, then per-dd
// table reads (12 VGPR live) feeding 8-row FMA chains.
__global__ __launch_bounds__(256, 4) void k_main(
    const float* __restrict__ data, const float* __restrict__ mask,
    const float* __restrict__ ws, float* __restrict__ part) {
  __shared__ float lds[DPB * 384];   // 24576 B

  const float* T = ws;
  int mt  = blockIdx.x / DSPLIT;
  int dsp = blockIdx.x % DSPLIT;
  int r0  = mt * BM + (threadIdx.x >> 5) * 8;
  int d0  = dsp * DPB;
  int kb  = (threadIdx.x & 31) << 2;

  const float* dbase = data + (size_t)r0 * ND + d0;
  const float* mbase = mask + (size_t)r0 * ND + d0;

  // stage the table slice: 16 dims * 384 floats = 1536 float4 (6/thread)
  {
    const float4* src = (const float4*)(T + (size_t)d0 * 384);
    float4* dst = (float4*)lds;
#pragma unroll
    for (int i = 0; i < 6; i++) dst[threadIdx.x + i * 256] = src[threadIdx.x + i * 256];
  }
  __syncthreads();

  float acc[8][4];
#pragma unroll
  for (int i = 0; i < 8; i++)
#pragma unroll
    for (int j = 0; j < 4; j++) acc[i][j] = 0.f;

#pragma unroll 1
  for (int dg = 0; dg < DPB; dg += 4) {
    // all x/m loads for this group issued together (one stall window)
    float4 xv[8], mv[8];
#pragma unroll
    for (int rr = 0; rr < 8; rr++) {
      xv[rr] = *(const float4*)(dbase + rr * ND + dg);
      mv[rr] = *(const float4*)(mbase + rr * ND + dg);
    }
#pragma unroll
    for (int dd = 0; dd < 4; dd++) {
      const float* base = lds + (dg + dd) * 384 + kb;
      float4 a = *(const float4*)(base);
      float4 b = *(const float4*)(base + 128);
      float4 c = *(const float4*)(base + 256);
#pragma unroll
      for (int rr = 0; rr < 8; rr++) {
        float x0 = (dd == 0) ? xv[rr].x : (dd == 1) ? xv[rr].y : (dd == 2) ? xv[rr].z : xv[rr].w;
        float m0 = (dd == 0) ? mv[rr].x : (dd == 1) ? mv[rr].y : (dd == 2) ? mv[rr].z : mv[rr].w;
        float m1 = m0 * x0;
        float m2 = m1 * x0;
        acc[rr][0] = fmaf(m2, a.x, fmaf(m1, b.x, fmaf(m0, c.x, acc[rr][0])));
        acc[rr][1] = fmaf(m2, a.y, fmaf(m1, b.y, fmaf(m0, c.y, acc[rr][1])));
        acc[rr][2] = fmaf(m2, a.z, fmaf(m1, b.z, fmaf(m0, c.z, acc[rr][2])));
        acc[rr][3] = fmaf(m2, a.w, fmaf(m1, b.w, fmaf(m0, c.w, acc[rr][3])));
      }
    }
  }

#pragma unroll
  for (int rr = 0; rr < 8; rr++) {
    float4 v = make_float4(acc[rr][0], acc[rr][1], acc[rr][2], acc[rr][3]);
    *(float4*)(part + ((size_t)dsp * NB + r0 + rr) * NK + kb) = v;
  }
}

// 2 rows per wave, float4 per lane (k-quad). Reduce DSPLIT partials, +log w,
// NaN fix, LSE with the reference's per-term +1e-8 (4e-8 per lane), exp.
__global__ __launch_bounds__(256) void k_final(
    const float* __restrict__ ws, float* __restrict__ out) {
  const float4* lw4   = (const float4*)(ws + TBL);
  const float4* part4 = (const float4*)(ws + TBL + NK);
  int lane = threadIdx.x & 63;
  int wv   = threadIdx.x >> 6;
  int half = lane >> 5;          // row within wave
  int lk   = lane & 31;          // k-quad index
  int b = blockIdx.x * 8 + wv * 2 + half;

  float4 s = make_float4(0.f, 0.f, 0.f, 0.f);
#pragma unroll
  for (int sp = 0; sp < DSPLIT; sp++) {
    float4 v = part4[((size_t)sp * NB + b) * 32 + lk];
    s.x += v.x; s.y += v.y; s.z += v.z; s.w += v.w;
  }
  float4 l = lw4[lk];
  s.x += l.x; s.y += l.y; s.z += l.z; s.w += l.w;
  if (isnan(s.x)) s.x = 0.f;
  if (isnan(s.y)) s.y = 0.f;
  if (isnan(s.z)) s.z = 0.f;
  if (isnan(s.w)) s.w = 0.f;

  float mx = fmaxf(fmaxf(s.x, s.y), fmaxf(s.z, s.w));
#pragma unroll
  for (int off = 16; off; off >>= 1) mx = fmaxf(mx, __shfl_xor(mx, off));
  float sum = expf(s.x - mx) + expf(s.y - mx) + expf(s.z - mx) + expf(s.w - mx) + 4e-8f;
#pragma unroll
  for (int off = 16; off; off >>= 1) sum += __shfl_xor(sum, off);
  float lse = logf(sum) + mx;
  float4 o = make_float4(expf(s.x - lse), expf(s.y - lse),
                         expf(s.z - lse), expf(s.w - lse));
  ((float4*)out)[(size_t)b * 32 + lk] = o;
}

extern "C" void kernel_launch(void* const* d_in, const int* in_sizes, int n_in,
                              void* d_out, int out_size, void* d_ws, size_t ws_size,
                              hipStream_t stream) {
  const float* data = (const float*)d_in[0];
  const float* mask = (const float*)d_in[1];
  const float* wts  = (const float*)d_in[2];
  const float* mu   = (const float*)d_in[3];
  const float* cov  = (const float*)d_in[4];
  float* ws   = (float*)d_ws;
  float* part = ws + TBL + NK;
  float* out  = (float*)d_out;

  k_tables<<<KD / 256, 256, 0, stream>>>(wts, mu, cov, ws);
  k_main<<<(NB / BM) * DSPLIT, 256, 0, stream>>>(data, mask, ws, part);
  k_final<<<NB / 8, 256, 0, stream>>>(ws, out);
}

// Round 7
// 40.698 us; speedup vs baseline: 4.0034x; 1.2369x over previous
//
#include <hip/hip_runtime.h>
#include <math.h>

#define NB 2048
#define ND 784
#define NK 128
#define BM 64               // rows per k_main block (8 ty x 8 rows each)
#define DSPLIT 49           // D chunks -> partials
#define DPB 16              // dims per block
#define KD (ND * NK)        // 100352
#define TBL (ND * 3 * NK)   // interleaved table floats = 301056

// ws layout (floats): T[TBL] | lw[NK] | part[DSPLIT*NB*NK]  (~52.6 MB)

__global__ __launch_bounds__(256) void k_tables(
    const float* __restrict__ w, const float* __restrict__ mu,
    const float* __restrict__ cov, float* __restrict__ ws) {
  int idx = blockIdx.x * 256 + threadIdx.x;   // grid covers KD exactly
  float* T  = ws;
  float* lw = ws + TBL;
  int d = idx >> 7;
  int k = idx & (NK - 1);
  float c = cov[k * ND + d];
  float m = mu[k * ND + d];
  float inv2 = 0.5f / c;
  T[d * 384 + k]       = -inv2;                           // ta
  T[d * 384 + 128 + k] = m / c;                           // tb
  T[d * 384 + 256 + k] = -m * m * inv2 - 0.5f * logf(c);  // tc
  if (idx < NK) lw[idx] = logf(w[idx]);
}

// Grid: (NB/BM)*DSPLIT = 32*49 = 1568 blocks, 256 threads.
// tx=tid&31 -> k-quad, ty=tid>>5 -> 8-row group.
// LDS = tables 16x384 (24576 B) + x[64][16] (4096 B) + m[64][16] (4096 B)
//     = 32768 B -> 4 blocks/CU = 16 waves/CU.
// Inner loop has ZERO global memory ops: tables read strided (12 cyc b128),
// x/m read broadcast (same addr per half-wave, ~free).
__global__ __launch_bounds__(256, 4) void k_main(
    const float* __restrict__ data, const float* __restrict__ mask,
    const float* __restrict__ ws, float* __restrict__ part) {
  __shared__ float lds_t[DPB * 384];   // 24576 B
  __shared__ float lds_x[BM * DPB];    // 4096 B
  __shared__ float lds_m[BM * DPB];    // 4096 B

  const float* T = ws;
  int mt  = blockIdx.x / DSPLIT;
  int dsp = blockIdx.x % DSPLIT;
  int gr0 = mt * BM;                    // block's first global row
  int lr0 = (threadIdx.x >> 5) * 8;    // this thread's first local row
  int d0  = dsp * DPB;
  int kb  = (threadIdx.x & 31) << 2;

  // stage x/m: 64 rows x 16 dims = 256 float4 each (1 per thread)
  {
    int row = threadIdx.x >> 2;        // 0..63
    int q   = threadIdx.x & 3;         // quad within row
    const float4* xs = (const float4*)(data + (size_t)(gr0 + row) * ND + d0);
    const float4* ms = (const float4*)(mask + (size_t)(gr0 + row) * ND + d0);
    ((float4*)lds_x)[threadIdx.x] = xs[q];
    ((float4*)lds_m)[threadIdx.x] = ms[q];
  }
  // stage tables: 16 dims * 384 floats = 1536 float4 (6/thread)
  {
    const float4* src = (const float4*)(T + (size_t)d0 * 384);
    float4* dst = (float4*)lds_t;
#pragma unroll
    for (int i = 0; i < 6; i++) dst[threadIdx.x + i * 256] = src[threadIdx.x + i * 256];
  }
  __syncthreads();

  float acc[8][4];
#pragma unroll
  for (int i = 0; i < 8; i++)
#pragma unroll
    for (int j = 0; j < 4; j++) acc[i][j] = 0.f;

#pragma unroll 1
  for (int dg = 0; dg < DPB; dg += 4) {
    float4 a[4], b[4], c[4];
#pragma unroll
    for (int dd = 0; dd < 4; dd++) {
      const float* base = lds_t + (dg + dd) * 384 + kb;
      a[dd] = *(const float4*)(base);
      b[dd] = *(const float4*)(base + 128);
      c[dd] = *(const float4*)(base + 256);
    }
#pragma unroll
    for (int rr = 0; rr < 8; rr++) {
      float4 x = *(const float4*)(lds_x + (lr0 + rr) * DPB + dg);
      float4 m = *(const float4*)(lds_m + (lr0 + rr) * DPB + dg);
      float xs[4] = {x.x, x.y, x.z, x.w};
      float ms[4] = {m.x, m.y, m.z, m.w};
#pragma unroll
      for (int dd = 0; dd < 4; dd++) {
        float m0 = ms[dd];
        float m1 = m0 * xs[dd];
        float m2 = m1 * xs[dd];
        acc[rr][0] = fmaf(m2, a[dd].x, fmaf(m1, b[dd].x, fmaf(m0, c[dd].x, acc[rr][0])));
        acc[rr][1] = fmaf(m2, a[dd].y, fmaf(m1, b[dd].y, fmaf(m0, c[dd].y, acc[rr][1])));
        acc[rr][2] = fmaf(m2, a[dd].z, fmaf(m1, b[dd].z, fmaf(m0, c[dd].z, acc[rr][2])));
        acc[rr][3] = fmaf(m2, a[dd].w, fmaf(m1, b[dd].w, fmaf(m0, c[dd].w, acc[rr][3])));
      }
    }
  }

#pragma unroll
  for (int rr = 0; rr < 8; rr++) {
    float4 v = make_float4(acc[rr][0], acc[rr][1], acc[rr][2], acc[rr][3]);
    *(float4*)(part + ((size_t)dsp * NB + gr0 + lr0 + rr) * NK + kb) = v;
  }
}

// 2 rows per wave, float4 per lane (k-quad). Reduce DSPLIT partials, +log w,
// NaN fix, LSE with the reference's per-term +1e-8 (4e-8 per lane), exp.
__global__ __launch_bounds__(256) void k_final(
    const float* __restrict__ ws, float* __restrict__ out) {
  const float4* lw4   = (const float4*)(ws + TBL);
  const float4* part4 = (const float4*)(ws + TBL + NK);
  int lane = threadIdx.x & 63;
  int wv   = threadIdx.x >> 6;
  int half = lane >> 5;          // row within wave
  int lk   = lane & 31;          // k-quad index
  int b = blockIdx.x * 8 + wv * 2 + half;

  float4 s = make_float4(0.f, 0.f, 0.f, 0.f);
#pragma unroll
  for (int sp = 0; sp < DSPLIT; sp++) {
    float4 v = part4[((size_t)sp * NB + b) * 32 + lk];
    s.x += v.x; s.y += v.y; s.z += v.z; s.w += v.w;
  }
  float4 l = lw4[lk];
  s.x += l.x; s.y += l.y; s.z += l.z; s.w += l.w;
  if (isnan(s.x)) s.x = 0.f;
  if (isnan(s.y)) s.y = 0.f;
  if (isnan(s.z)) s.z = 0.f;
  if (isnan(s.w)) s.w = 0.f;

  float mx = fmaxf(fmaxf(s.x, s.y), fmaxf(s.z, s.w));
#pragma unroll
  for (int off = 16; off; off >>= 1) mx = fmaxf(mx, __shfl_xor(mx, off));
  float sum = expf(s.x - mx) + expf(s.y - mx) + expf(s.z - mx) + expf(s.w - mx) + 4e-8f;
#pragma unroll
  for (int off = 16; off; off >>= 1) sum += __shfl_xor(sum, off);
  float lse = logf(sum) + mx;
  float4 o = make_float4(expf(s.x - lse), expf(s.y - lse),
                         expf(s.z - lse), expf(s.w - lse));
  ((float4*)out)[(size_t)b * 32 + lk] = o;
}

extern "C" void kernel_launch(void* const* d_in, const int* in_sizes, int n_in,
                              void* d_out, int out_size, void* d_ws, size_t ws_size,
                              hipStream_t stream) {
  const float* data = (const float*)d_in[0];
  const float* mask = (const float*)d_in[1];
  const float* wts  = (const float*)d_in[2];
  const float* mu   = (const float*)d_in[3];
  const float* cov  = (const float*)d_in[4];
  float* ws   = (float*)d_ws;
  float* part = ws + TBL + NK;
  float* out  = (float*)d_out;

  k_tables<<<KD / 256, 256, 0, stream>>>(wts, mu, cov, ws);
  k_main<<<(NB / BM) * DSPLIT, 256, 0, stream>>>(data, mask, ws, part);
  k_final<<<NB / 8, 256, 0, stream>>>(ws, out);
}

// Round 8
// 35.119 us; speedup vs baseline: 4.6395x; 1.1589x over previous
//
#include <hip/hip_runtime.h>
#include <math.h>

#define NB 2048
#define ND 784
#define NK 128
#define KP 2400            // padded GEMM K: 3*784=2352 -> 2400 = 12*200 = 32*75
#define NSTEP 75           // KP/32 k-steps
#define KSPLIT 15          // K-chunks -> partials
#define SPK 5              // k-steps per chunk = NSTEP/KSPLIT

typedef __attribute__((ext_vector_type(8))) short short8;
typedef __attribute__((ext_vector_type(4))) float f32x4;

// ws float offsets:
#define OFF_LW   0
#define N_PART   (KSPLIT * NB * NK)          // 3,932,160 floats
#define OFF_PART 128
#define OFF_AH   (OFF_PART + N_PART)
#define N_A_F    (NB * KP / 2)               // 2,457,600 float slots (ushort/2)
#define OFF_AL   (OFF_AH + N_A_F)
#define OFF_BH   (OFF_AL + N_A_F)
#define N_B_F    (NSTEP * 8 * 64 * 8 / 2)    // 153,600 float slots
#define OFF_BL   (OFF_BH + N_B_F)
// total ~9.15M floats ~= 36.6 MB

__device__ inline ushort f2bf(float f) {     // round-to-nearest-even f32->bf16
  uint u = __float_as_uint(f);
  return (ushort)((u + 0x7FFFu + ((u >> 16) & 1u)) >> 16);
}

// B-prep: tables in bf16 hi/lo, FRAGMENT-LINEAR layout.
// Fragment fid = ks*8 + nt; lane l holds B[K = ks*32 + (l>>4)*8 + j][n = nt*16 + (l&15)],
// j=0..7, stored as 8 ushorts at ((fid*64)+l)*8.  K>=2352 -> 0.
__global__ __launch_bounds__(256) void k_bprep(
    const float* __restrict__ w, const float* __restrict__ mu,
    const float* __restrict__ cov, float* __restrict__ ws) {
  int tid = blockIdx.x * 256 + threadIdx.x;   // 0..38399
  if (tid < NK) ws[OFF_LW + tid] = logf(w[tid]);
  int l   = tid & 63;
  int fid = tid >> 6;          // 0..599
  int nt  = fid & 7;
  int ks  = fid >> 3;          // 0..74
  int n   = nt * 16 + (l & 15);
  int K0  = ks * 32 + ((l >> 4) << 3);
  ushort hi[8], lo[8];
#pragma unroll
  for (int j = 0; j < 8; j++) {
    int K = K0 + j;
    float v = 0.f;
    if (K < 3 * ND) {
      int d = K / 3;
      int c = K - 3 * d;
      float cv = cov[n * ND + d];
      float mv = mu[n * ND + d];
      v = (c == 0) ? (-0.5f / cv)
        : (c == 1) ? (mv / cv)
                   : (-mv * mv * 0.5f / cv - 0.5f * logf(cv));
    }
    ushort h = f2bf(v);
    hi[j] = h;
    lo[j] = f2bf(v - __uint_as_float(((uint)h) << 16));
  }
  uint4 vh, vl;
  vh.x = (uint)hi[0] | ((uint)hi[1] << 16);
  vh.y = (uint)hi[2] | ((uint)hi[3] << 16);
  vh.z = (uint)hi[4] | ((uint)hi[5] << 16);
  vh.w = (uint)hi[6] | ((uint)hi[7] << 16);
  vl.x = (uint)lo[0] | ((uint)lo[1] << 16);
  vl.y = (uint)lo[2] | ((uint)lo[3] << 16);
  vl.z = (uint)lo[4] | ((uint)lo[5] << 16);
  vl.w = (uint)lo[6] | ((uint)lo[7] << 16);
  ((uint4*)(ws + OFF_BH))[fid * 64 + l] = vh;
  ((uint4*)(ws + OFF_BL))[fid * 64 + l] = vl;
}

// A-prep: A[b][K] bf16 hi/lo, row-major [NB][KP].
// K = 12*dq + 3*dd + c with vals {m*x^2, m*x, m}; dq>=196 -> zero pad.
__global__ __launch_bounds__(256) void k_aprep(
    const float* __restrict__ data, const float* __restrict__ mask,
    float* __restrict__ ws) {
  int tid = blockIdx.x * 256 + threadIdx.x;   // 0..409599
  int b  = tid / 200;
  int dq = tid - b * 200;
  float vals[12];
  if (dq < 196) {
    float4 x = *(const float4*)(data + (size_t)b * ND + 4 * dq);
    float4 m = *(const float4*)(mask + (size_t)b * ND + 4 * dq);
    float xs[4] = {x.x, x.y, x.z, x.w};
    float ms[4] = {m.x, m.y, m.z, m.w};
#pragma unroll
    for (int dd = 0; dd < 4; dd++) {
      float mm = ms[dd], xx = xs[dd];
      float mx = mm * xx;
      vals[3 * dd]     = mx * xx;
      vals[3 * dd + 1] = mx;
      vals[3 * dd + 2] = mm;
    }
  } else {
#pragma unroll
    for (int i = 0; i < 12; i++) vals[i] = 0.f;
  }
  uint ah[6], al[6];
#pragma unroll
  for (int i = 0; i < 6; i++) {
    ushort h0 = f2bf(vals[2 * i]), h1 = f2bf(vals[2 * i + 1]);
    float r0 = vals[2 * i]     - __uint_as_float(((uint)h0) << 16);
    float r1 = vals[2 * i + 1] - __uint_as_float(((uint)h1) << 16);
    ushort l0 = f2bf(r0), l1 = f2bf(r1);
    ah[i] = (uint)h0 | ((uint)h1 << 16);
    al[i] = (uint)l0 | ((uint)l1 << 16);
  }
  uint* Ahu = (uint*)(ws + OFF_AH) + (size_t)b * (KP / 2) + 6 * dq;
  uint* Alu = (uint*)(ws + OFF_AL) + (size_t)b * (KP / 2) + 6 * dq;
#pragma unroll
  for (int i = 0; i < 3; i++) {
    ((uint2*)Ahu)[i] = make_uint2(ah[2 * i], ah[2 * i + 1]);
    ((uint2*)Alu)[i] = make_uint2(al[2 * i], al[2 * i + 1]);
  }
}

// GEMM: grid 32 M-tiles x KSPLIT. Block = 4 waves; wave w owns rows
// r0 = mt*64 + w*16, all 128 cols, K-chunk of SPK k-steps. No LDS, no barriers.
// A-frag: lane l = A[r0+(l&15)][ks*32 + (l>>4)*8 + 0..7]; B-frag fragment-linear.
// acc layout (m89): col = lane&15, row = (lane>>4)*4 + reg.
__global__ __launch_bounds__(256) void k_mm(float* __restrict__ ws) {
  const ushort* Ah = (const ushort*)(ws + OFF_AH);
  const ushort* Al = (const ushort*)(ws + OFF_AL);
  const short8* Bh = (const short8*)(ws + OFF_BH);
  const short8* Bl = (const short8*)(ws + OFF_BL);
  float* part = ws + OFF_PART;

  int mt = blockIdx.x / KSPLIT;
  int kc = blockIdx.x % KSPLIT;
  int w  = threadIdx.x >> 6;
  int l  = threadIdx.x & 63;
  int r0 = mt * 64 + w * 16;
  int rowA = r0 + (l & 15);

  f32x4 acc[8];
#pragma unroll
  for (int i = 0; i < 8; i++) acc[i] = (f32x4){0.f, 0.f, 0.f, 0.f};

  const ushort* pAh = Ah + (size_t)rowA * KP + ((l >> 4) << 3);
  const ushort* pAl = Al + (size_t)rowA * KP + ((l >> 4) << 3);

#pragma unroll
  for (int s = 0; s < SPK; s++) {
    int ks = kc * SPK + s;
    short8 a_h = *(const short8*)(pAh + ks * 32);
    short8 a_l = *(const short8*)(pAl + ks * 32);
    const short8* bh = Bh + (size_t)(ks * 8) * 64 + l;
    const short8* bl = Bl + (size_t)(ks * 8) * 64 + l;
#pragma unroll
    for (int nt = 0; nt < 8; nt++) {
      short8 b_h = bh[nt * 64];
      short8 b_l = bl[nt * 64];
      acc[nt] = __builtin_amdgcn_mfma_f32_16x16x32_bf16(a_h, b_h, acc[nt], 0, 0, 0);
      acc[nt] = __builtin_amdgcn_mfma_f32_16x16x32_bf16(a_h, b_l, acc[nt], 0, 0, 0);
      acc[nt] = __builtin_amdgcn_mfma_f32_16x16x32_bf16(a_l, b_h, acc[nt], 0, 0, 0);
    }
  }

#pragma unroll
  for (int nt = 0; nt < 8; nt++)
#pragma unroll
    for (int r = 0; r < 4; r++) {
      int grow = r0 + ((l >> 4) << 2) + r;
      part[((size_t)kc * NB + grow) * NK + nt * 16 + (l & 15)] = acc[nt][r];
    }
}

// 2 rows per wave, float4 per lane (k-quad). Reduce KSPLIT partials, +log w,
// NaN fix, LSE with the reference's per-term +1e-8 (4e-8 per lane), exp.
__global__ __launch_bounds__(256) void k_final(
    const float* __restrict__ ws, float* __restrict__ out) {
  const float4* lw4   = (const float4*)(ws + OFF_LW);
  const float4* part4 = (const float4*)(ws + OFF_PART);
  int lane = threadIdx.x & 63;
  int wv   = threadIdx.x >> 6;
  int half = lane >> 5;
  int lk   = lane & 31;
  int b = blockIdx.x * 8 + wv * 2 + half;

  float4 s = make_float4(0.f, 0.f, 0.f, 0.f);
#pragma unroll
  for (int sp = 0; sp < KSPLIT; sp++) {
    float4 v = part4[((size_t)sp * NB + b) * 32 + lk];
    s.x += v.x; s.y += v.y; s.z += v.z; s.w += v.w;
  }
  float4 lv = lw4[lk];
  s.x += lv.x; s.y += lv.y; s.z += lv.z; s.w += lv.w;
  if (isnan(s.x)) s.x = 0.f;
  if (isnan(s.y)) s.y = 0.f;
  if (isnan(s.z)) s.z = 0.f;
  if (isnan(s.w)) s.w = 0.f;

  float mx = fmaxf(fmaxf(s.x, s.y), fmaxf(s.z, s.w));
#pragma unroll
  for (int off = 16; off; off >>= 1) mx = fmaxf(mx, __shfl_xor(mx, off));
  float sum = expf(s.x - mx) + expf(s.y - mx) + expf(s.z - mx) + expf(s.w - mx) + 4e-8f;
#pragma unroll
  for (int off = 16; off; off >>= 1) sum += __shfl_xor(sum, off);
  float lse = logf(sum) + mx;
  float4 o = make_float4(expf(s.x - lse), expf(s.y - lse),
                         expf(s.z - lse), expf(s.w - lse));
  ((float4*)out)[(size_t)b * 32 + lk] = o;
}

extern "C" void kernel_launch(void* const* d_in, const int* in_sizes, int n_in,
                              void* d_out, int out_size, void* d_ws, size_t ws_size,
                              hipStream_t stream) {
  const float* data = (const float*)d_in[0];
  const float* mask = (const float*)d_in[1];
  const float* wts  = (const float*)d_in[2];
  const float* mu   = (const float*)d_in[3];
  const float* cov  = (const float*)d_in[4];
  float* ws  = (float*)d_ws;
  float* out = (float*)d_out;

  k_bprep<<<150, 256, 0, stream>>>(wts, mu, cov, ws);
  k_aprep<<<1600, 256, 0, stream>>>(data, mask, ws);
  k_mm<<<32 * KSPLIT, 256, 0, stream>>>(ws);
  k_final<<<NB / 8, 256, 0, stream>>>(ws, out);
}